// Round 6
// baseline (962.255 us; speedup 1.0000x reference)
//
#include <hip/hip_runtime.h>
#include <hip/hip_bf16.h>

// ---------------------------------------------------------------------------
// Spatial_AttLayer on MI355X (gfx950), bf16 MFMA.
//
// Round-6: regime change. Five prior versions all ran 1 WG/CU (2 waves/SIMD)
// and all landed ~250-320 us with every pipe <25% busy -- latency-exposed.
// This version:
//   * 2 WGs/CU (LDS 76.8 KB/WG: single Fl, half-K Zl; GEMM2/3 run twice per
//     tile over head-halves) -> 4 waves/SIMD, 512 WGs x 8 iterations.
//   * designed for <=128 VGPRs: NO pinned weight arrays. Wo/Wv fragments
//     stream from L2 via rolling distance-2 unrolled prefetch (static idx).
//   * XOR-swizzled LDS tiles (off ^= (row&7)<<3 shorts): the stride-264/520
//     layouts had 4-8-way ds_read_b128 bank conflicts (SQ_LDS_BANK_CONFLICT
//     frozen at 1.42e7 across all rounds); swizzle makes them <=2-way (free).
// Chain per tile (64 cols = 2 t's, vp 25->32 zero-padded):
//   Vm = Wv@F + bv ; for H in {0,1}: Z_H = Vm@[A_{4H}..A_{4H+3}] ;
//   acc += Wo[:,256H:256H+256] @ Z_H ;  out = acc (+bo+F residual init)
// ---------------------------------------------------------------------------

typedef __attribute__((ext_vector_type(8))) short short8;
typedef __attribute__((ext_vector_type(4))) short short4v;
typedef __attribute__((ext_vector_type(4))) float f4v;

static __device__ __forceinline__ unsigned short f2bf(float f) {
  union { float f; unsigned u; } v; v.f = f;
  unsigned r = v.u + 0x7fffu + ((v.u >> 16) & 1u);   // RNE
  return (unsigned short)(r >> 16);
}
static __device__ __forceinline__ float bf2f(unsigned short h) {
  union { unsigned u; float f; } v; v.u = ((unsigned)h) << 16;
  return v.f;
}

// ws layout (unsigned short units unless noted):
//   WvP   [64][256]        bf16                               16384 elems
//   WoP   [256][512]       bf16 (plain cast, native order)   131072 elems
//   attnP [8][32][40]      bf16 (B-layout [vp][u], zero-pad)  10240 elems
//   qkP   [2][8][64][25]   f32 (q then k)                     25600 floats

// ---------------------------------------------------------------------------
// Kernel 1a: q/k 1x1 conv (one dot per thread) + weight conversions.
__global__ void k_qk_conv(const float* __restrict__ tf,
                          const float* __restrict__ Wq, const float* __restrict__ bq,
                          const float* __restrict__ Wk, const float* __restrict__ bk,
                          const float* __restrict__ Wv, const float* __restrict__ Wo,
                          unsigned short* __restrict__ WvP,
                          unsigned short* __restrict__ WoP,
                          float* __restrict__ qkP)
{
  __shared__ float tfl[12800];
  const int b = blockIdx.x, tid = threadIdx.x;
  if (b < 100) {
    for (int i = tid; i < 12800; i += 256) tfl[i] = tf[i];
    __syncthreads();
    int idx = b * 256 + tid;                    // 0..25599
    int isK = idx >= 12800;
    int j = isK ? idx - 12800 : idx;
    int g = j / 25, u = j - 25 * g;             // g: 0..511
    const float* wrow = (isK ? Wk : Wq) + g * 512;
    float s = (isK ? bk : bq)[g];
    for (int i = 0; i < 512; ++i) s += wrow[i] * tfl[i * 25 + u];
    qkP[idx] = s;
  } else {
    int cb = b - 100;                           // 0..63
    for (int i = cb * 256 + tid; i < 16384; i += 64 * 256) {
      WvP[i] = f2bf(Wv[i]);                     // [c][k] row-major, same as Wv
    }
    for (int i = cb * 256 + tid; i < 131072; i += 64 * 256) {
      WoP[i] = f2bf(Wo[i]);                     // native [o][h*64+c] order
    }
  }
}

// ---------------------------------------------------------------------------
// Kernel 1b: energy + softmax per head -> attnP (zero-padded B-layout).
__global__ void k_attn(const float* __restrict__ qkP,
                       unsigned short* __restrict__ attnP)
{
  __shared__ float ql[1600], kl[1600], attl[625];
  const int h = blockIdx.x, tid = threadIdx.x;
  for (int i = tid; i < 1600; i += 256) {
    ql[i] = qkP[h * 1600 + i];
    kl[i] = qkP[12800 + h * 1600 + i];
  }
  __syncthreads();
  if (tid < 25) {
    int u = tid;
    float e[25];
    float mx = -1e30f;
    #pragma unroll
    for (int v = 0; v < 25; ++v) {
      float s = 0.f;
      #pragma unroll
      for (int r = 0; r < 64; ++r) s += ql[r * 25 + u] * kl[r * 25 + v];
      s *= 0.125f;                              // 1/sqrt(64)
      e[v] = s;
      mx = fmaxf(mx, s);
    }
    float den = 0.f;
    #pragma unroll
    for (int v = 0; v < 25; ++v) { e[v] = __expf(e[v] - mx); den += e[v]; }
    float inv = 1.f / den;
    #pragma unroll
    for (int v = 0; v < 25; ++v) attl[u * 25 + v] = e[v] * inv;
  }
  __syncthreads();
  // attnP[h][vp][u] = attn[u][vp]; zero where u>=25 or vp>=25
  for (int i = tid; i < 1280; i += 256) {
    int vp = i / 40, u = i - 40 * vp;
    attnP[h * 1280 + i] =
        (vp < 25 && u < 25) ? f2bf(attl[u * 25 + vp]) : (unsigned short)0;
  }
}

// ---------------------------------------------------------------------------
// Main fused kernel. 512 threads (8 waves), 2 WGs/CU (LDS 76800 B, VGPR<=128).
// LDS: Fl [64 cols][264] @0 (swz) | Vl [64 c][72] @33792 (swz)
//      | Zl [64 cols][264] @43008 (swz, half-K)
// swizzle: element offset within a row ^= (row&7)<<3  (16B-preserving)
__launch_bounds__(512, 4)
__global__ void k_main(const float* __restrict__ feature,
                       const float* __restrict__ bv,
                       const float* __restrict__ bo,
                       const unsigned short* __restrict__ WvP,
                       const unsigned short* __restrict__ WoP,
                       const unsigned short* __restrict__ attnP,
                       float* __restrict__ out)
{
  extern __shared__ char smem[];
  unsigned short* Fl = (unsigned short*)smem;             // [64][264] swz
  unsigned short* Vl = (unsigned short*)(smem + 33792);   // [64][72]  swz
  unsigned short* Zl = (unsigned short*)(smem + 43008);   // [64][264] swz

  const int tid  = threadIdx.x;
  const int wave = tid >> 6;
  const int lane = tid & 63;
  const int quad = lane >> 4;
  const int l16  = lane & 15;
  const int wg    = blockIdx.x;
  const int n     = wg & 7;                    // one batch image per XCD
  const int chunk = wg >> 3;                   // 0..63; t0 = chunk*16 + it*2

  const int c = tid >> 1, p = tid & 1;
  const size_t rowbase = ((size_t)(n * 256 + c) * 1024) * 25;   // floats

  // GEMM1 wave grid
  const int mt1 = wave & 3, nh1 = wave >> 2;
  // GEMM2 wave grid (per head-half): local head + mi-pair base
  const int hl  = wave & 3;
  const int mig = (wave >> 2) * 2;
  // persistent attn fragments: ab[H][vph]  (h = H*4 + hl)
  short8 ab[2][2];
  #pragma unroll
  for (int H = 0; H < 2; ++H)
    #pragma unroll
    for (int vph = 0; vph < 2; ++vph)
      ab[H][vph] = *reinterpret_cast<const short8*>(
          attnP + (H * 4 + hl) * 1280 + (vph * 16 + l16) * 40 + quad * 8);

  float bo4[2][4];
  #pragma unroll
  for (int mi = 0; mi < 2; ++mi)
    #pragma unroll
    for (int r = 0; r < 4; ++r) bo4[mi][r] = bo[wave * 32 + mi * 16 + quad * 4 + r];
  float bvv[4];
  #pragma unroll
  for (int r = 0; r < 4; ++r) bvv[r] = bv[mt1 * 16 + quad * 4 + r];

  // Wo stream base for this wave: row = wave*32 + l16 (+16 for mi=1)
  const unsigned short* wob = WoP + (wave * 32 + l16) * 512 + quad * 8;
  // Wv stream base
  const unsigned short* wvb = WvP + (mt1 * 16 + l16) * 256 + quad * 8;

  // ---- zero Fl pad cols (vp 25..31, both t); swizzle is a bijection on the
  //      256-elem c-range, so linear zeroing covers exactly the pad cells ----
  {
    short8 z = {0, 0, 0, 0, 0, 0, 0, 0};
    for (int i = tid; i < 448; i += 512) {     // 14 pad cols x 32 short8
      int pc = i >> 5, off = i & 31;           // pc 0..13
      int t = pc / 7, vp = 25 + (pc - 7 * t);
      *reinterpret_cast<short8*>(&Fl[(t * 32 + vp) * 264 + off * 8]) = z;
    }
  }

  // ---- prologue: load + stage block 0 into Fl (swizzled) ----
  {
    float2 f0[13];
    const float2* s2 = reinterpret_cast<const float2*>(
        feature + rowbase + (size_t)(chunk * 16) * 25);
    #pragma unroll
    for (int j = 0; j < 13; ++j) { int i = p + 2 * j; if (i < 25) f0[j] = s2[i]; }
    #pragma unroll
    for (int j = 0; j < 13; ++j) {
      int i = p + 2 * j;
      if (i < 25) {
        int j0 = 2 * i;
        { int jj = j0;     int t = (jj >= 25); int vp = jj - 25 * t; int col = t*32+vp;
          Fl[col * 264 + (c ^ ((col & 7) << 3))] = f2bf(f0[j].x); }
        { int jj = j0 + 1; int t = (jj >= 25); int vp = jj - 25 * t; int col = t*32+vp;
          Fl[col * 264 + (c ^ ((col & 7) << 3))] = f2bf(f0[j].y); }
      }
    }
  }
  __syncthreads();

  // ---- loop over 8 t-blocks (4 barriers per iteration) ----
  #pragma unroll 1
  for (int it = 0; it < 8; ++it) {
    const int t0 = chunk * 16 + it * 2;

    // (A) issue next block's feature loads; pin above compute
    float2 fn[13];
    if (it < 7) {
      const float2* s2 = reinterpret_cast<const float2*>(
          feature + rowbase + (size_t)(t0 + 2) * 25);
      #pragma unroll
      for (int j = 0; j < 13; ++j) { int i = p + 2 * j; if (i < 25) fn[j] = s2[i]; }
      __builtin_amdgcn_sched_barrier(0);
    }

    // (B) GEMM1: Vm = Wv@F + bv -> Vl. Wv streamed, rolling distance-2.
    {
      f4v accv[2];
      #pragma unroll
      for (int ni = 0; ni < 2; ++ni)
        #pragma unroll
        for (int r = 0; r < 4; ++r) accv[ni][r] = bvv[r];
      short8 wap[2];
      wap[0] = *reinterpret_cast<const short8*>(wvb);
      wap[1] = *reinterpret_cast<const short8*>(wvb + 32);
      #pragma unroll
      for (int ks = 0; ks < 8; ++ks) {
        short8 a = wap[ks & 1];
        if (ks < 6)
          wap[ks & 1] = *reinterpret_cast<const short8*>(wvb + (ks + 2) * 32);
        #pragma unroll
        for (int ni = 0; ni < 2; ++ni) {
          int colb = (2 * nh1 + ni) * 16 + l16;
          short8 b = *reinterpret_cast<const short8*>(
              &Fl[colb * 264 + ((ks * 32 + quad * 8) ^ ((l16 & 7) << 3))]);
          accv[ni] = __builtin_amdgcn_mfma_f32_16x16x32_bf16(a, b, accv[ni], 0, 0, 0);
        }
      }
      #pragma unroll
      for (int ni = 0; ni < 2; ++ni) {
        int colb = (2 * nh1 + ni) * 16 + l16;
        #pragma unroll
        for (int r = 0; r < 4; ++r) {
          int cc = mt1 * 16 + quad * 4 + r;
          Vl[cc * 72 + (colb ^ ((cc & 7) << 3))] = f2bf(accv[ni][r]);
        }
      }
    }

    // (D) acc init: bias + residual from Fl (alive until barrier 1)
    f4v acc[2][4];
    #pragma unroll
    for (int mi = 0; mi < 2; ++mi) {
      const int o0 = wave * 32 + mi * 16 + quad * 4;
      #pragma unroll
      for (int ni = 0; ni < 4; ++ni) {
        int colb = ni * 16 + l16;
        short4v fr = *reinterpret_cast<const short4v*>(
            &Fl[colb * 264 + (o0 ^ ((l16 & 7) << 3))]);
        #pragma unroll
        for (int r = 0; r < 4; ++r)
          acc[mi][ni][r] = bo4[mi][r] + bf2f((unsigned short)fr[r]);
      }
    }
    __syncthreads();                           // bar1: Vl ready, Fl consumed

    // (C) commit next F block into Fl (readers are in it+1, past bar2..4)
    if (it < 7) {
      #pragma unroll
      for (int j = 0; j < 13; ++j) {
        int i = p + 2 * j;
        if (i < 25) {
          int j0 = 2 * i;
          { int jj = j0;     int t = (jj >= 25); int vp = jj - 25 * t; int col = t*32+vp;
            Fl[col * 264 + (c ^ ((col & 7) << 3))] = f2bf(fn[j].x); }
          { int jj = j0 + 1; int t = (jj >= 25); int vp = jj - 25 * t; int col = t*32+vp;
            Fl[col * 264 + (c ^ ((col & 7) << 3))] = f2bf(fn[j].y); }
        }
      }
    }

    // ---- two head-halves: {GEMM2 -> bar -> GEMM3 -> bar} x 2 ----
    #pragma unroll
    for (int H = 0; H < 2; ++H) {
      // (E) GEMM2 half H: Z = Vm @ [A_{4H}..A_{4H+3}] -> Zl (local k 0..255)
      #pragma unroll
      for (int mo = 0; mo < 2; ++mo) {
        const int mi2 = mig + mo;
        #pragma unroll
        for (int t = 0; t < 2; ++t) {
          const int row = mi2 * 16 + l16;
          short8 a = *reinterpret_cast<const short8*>(
              &Vl[row * 72 + ((t * 32 + quad * 8) ^ ((l16 & 7) << 3))]);
          #pragma unroll
          for (int vph = 0; vph < 2; ++vph) {
            f4v z = {0.f, 0.f, 0.f, 0.f};
            f4v az = __builtin_amdgcn_mfma_f32_16x16x32_bf16(a, ab[H][vph], z, 0, 0, 0);
            int col = t * 32 + vph * 16 + l16;
            int k0 = hl * 64 + mi2 * 16 + quad * 4;
            short4v zz;
            #pragma unroll
            for (int r = 0; r < 4; ++r) zz[r] = (short)f2bf(az[r]);
            *reinterpret_cast<short4v*>(
                &Zl[col * 264 + (k0 ^ ((col & 7) << 3))]) = zz;
          }
        }
      }
      __syncthreads();                         // Zl half ready

      // (F) GEMM3 half H: acc += Wo[:, 256H:256H+256] @ Z_H.
      //     Wo streamed from L2: 4 frags upfront, rolling distance-2.
      {
        const unsigned short* wb = wob + H * 256;
        short8 wop[2][2];                      // [parity][mi]
        wop[0][0] = *reinterpret_cast<const short8*>(wb);
        wop[0][1] = *reinterpret_cast<const short8*>(wb + 8192);
        wop[1][0] = *reinterpret_cast<const short8*>(wb + 32);
        wop[1][1] = *reinterpret_cast<const short8*>(wb + 8192 + 32);
        #pragma unroll
        for (int ksl = 0; ksl < 8; ++ksl) {
          short8 w0 = wop[ksl & 1][0];
          short8 w1 = wop[ksl & 1][1];
          if (ksl < 6) {
            wop[ksl & 1][0] = *reinterpret_cast<const short8*>(wb + (ksl + 2) * 32);
            wop[ksl & 1][1] = *reinterpret_cast<const short8*>(wb + 8192 + (ksl + 2) * 32);
          }
          #pragma unroll
          for (int ni = 0; ni < 4; ++ni) {
            int row = ni * 16 + l16;
            short8 bfr = *reinterpret_cast<const short8*>(
                &Zl[row * 264 + ((ksl * 32 + quad * 8) ^ ((l16 & 7) << 3))]);
            acc[0][ni] = __builtin_amdgcn_mfma_f32_16x16x32_bf16(w0, bfr, acc[0][ni], 0, 0, 0);
            acc[1][ni] = __builtin_amdgcn_mfma_f32_16x16x32_bf16(w1, bfr, acc[1][ni], 0, 0, 0);
          }
        }
      }
      __syncthreads();                         // Zl consumed (reusable)
    }

    // epilogue: store fp32, skip vp pads
    #pragma unroll
    for (int ni = 0; ni < 4; ++ni) {
      int colb = ni * 16 + l16;
      int t = colb >> 5, vp = colb & 31;
      if (vp < 25) {
        #pragma unroll
        for (int mi = 0; mi < 2; ++mi)
          #pragma unroll
          for (int r = 0; r < 4; ++r) {
            int o = wave * 32 + mi * 16 + quad * 4 + r;
            out[((size_t)(n * 256 + o) * 1024 + (t0 + t)) * 25 + vp] = acc[mi][ni][r];
          }
      }
    }
    // next iteration's bar1 orders Fl/Vl/Zl reuse.
  }
}

// ---------------------------------------------------------------------------
extern "C" void kernel_launch(void* const* d_in, const int* in_sizes, int n_in,
                              void* d_out, int out_size, void* d_ws, size_t ws_size,
                              hipStream_t stream)
{
  const float* feature = (const float*)d_in[0];
  const float* tf      = (const float*)d_in[1];
  const float* Wq      = (const float*)d_in[2];
  const float* bq      = (const float*)d_in[3];
  const float* Wk      = (const float*)d_in[4];
  const float* bk      = (const float*)d_in[5];
  const float* Wv      = (const float*)d_in[6];
  const float* bv      = (const float*)d_in[7];
  const float* Wo      = (const float*)d_in[8];
  const float* bo      = (const float*)d_in[9];
  float* out = (float*)d_out;

  unsigned short* WvP   = (unsigned short*)d_ws;        // 16384
  unsigned short* WoP   = WvP + 16384;                  // 131072
  unsigned short* attnP = WoP + 131072;                 // 10240
  float* qkP = (float*)(attnP + 10240);                 // 25600 floats

  hipLaunchKernelGGL(k_qk_conv, dim3(164), dim3(256), 0, stream,
                     tf, Wq, bq, Wk, bk, Wv, Wo, WvP, WoP, qkP);
  hipLaunchKernelGGL(k_attn, dim3(8), dim3(256), 0, stream, qkP, attnP);

  hipFuncSetAttribute(reinterpret_cast<const void*>(&k_main),
                      hipFuncAttributeMaxDynamicSharedMemorySize, 76800);
  hipLaunchKernelGGL(k_main, dim3(512), dim3(512), 76800, stream,
                     feature, bv, bo, WvP, WoP, attnP, out);
}

// Round 7
// 595.749 us; speedup vs baseline: 1.6152x; 1.6152x over previous
//
#include <hip/hip_runtime.h>
#include <hip/hip_bf16.h>

// ---------------------------------------------------------------------------
// Spatial_AttLayer on MI355X (gfx950), bf16 MFMA.
//
// Round-7: split the fused chain. Seven fused variants all sat at 246-320 us,
// latency-exposed (all pipes <25%): the stage->GEMM1->GEMM2->GEMM3 barrier
// chain serializes every iteration. New structure:
//   k_vm:   V = Wv@F + bv for all (n,t) -> workspace [n][t][c'][32] bf16.
//           4096 independent WGs, 1 barrier, 4 WGs/CU. Pure stream.
//   k_main: per 64-col tile: GEMM2 (V-frags read DIRECTLY from global; the
//           V layout makes MFMA A-fragments 16B-contiguous) -> Zl ->
//           ONE barrier -> GEMM3 (rolling Wo prefetch from L2). Residual +
//           bias loads issued in the barrier shadow. 4096 independent WGs,
//           LDS = Zl only (66.6 KB -> 2 WGs/CU = 4 waves/SIMD).
//   amdgpu_waves_per_eu(4,4) on both: pins the allocator's occupancy target
//   (r3/r4/r6 all mis-allocated because the heuristic can't see dynamic LDS;
//   r5 proved the attribute is the lever that actually changes codegen).
//   No LDS swizzles: stride 264/520 (=4 dwords mod 32) is already uniform
//   for the b128 read patterns (r6's XOR made conflicts 4x WORSE).
// ---------------------------------------------------------------------------

typedef __attribute__((ext_vector_type(8))) short short8;
typedef __attribute__((ext_vector_type(4))) short short4v;
typedef __attribute__((ext_vector_type(4))) float f4v;

static __device__ __forceinline__ unsigned short f2bf(float f) {
  union { float f; unsigned u; } v; v.f = f;
  unsigned r = v.u + 0x7fffu + ((v.u >> 16) & 1u);   // RNE
  return (unsigned short)(r >> 16);
}

// ws layout:
//   WvP   [64][256]        bf16   16384 elems   (native Wv order)
//   WoP   [256][512]       bf16  131072 elems   (native Wo order)
//   attnP [8][32][40]      bf16   10240 elems   (B-layout [vp][u], zero-pad)
//   qkP   [2][8][64][25]   f32    25600 floats
//   Vws   [8][1024][64][32] bf16  16777216 elems (u padded 25->32)

// ---------------------------------------------------------------------------
// Kernel 1a: q/k 1x1 conv (one dot per thread) + weight conversions.
__global__ void k_qk_conv(const float* __restrict__ tf,
                          const float* __restrict__ Wq, const float* __restrict__ bq,
                          const float* __restrict__ Wk, const float* __restrict__ bk,
                          const float* __restrict__ Wv, const float* __restrict__ Wo,
                          unsigned short* __restrict__ WvP,
                          unsigned short* __restrict__ WoP,
                          float* __restrict__ qkP)
{
  __shared__ float tfl[12800];
  const int b = blockIdx.x, tid = threadIdx.x;
  if (b < 100) {
    for (int i = tid; i < 12800; i += 256) tfl[i] = tf[i];
    __syncthreads();
    int idx = b * 256 + tid;                    // 0..25599
    int isK = idx >= 12800;
    int j = isK ? idx - 12800 : idx;
    int g = j / 25, u = j - 25 * g;             // g: 0..511
    const float* wrow = (isK ? Wk : Wq) + g * 512;
    float s = (isK ? bk : bq)[g];
    for (int i = 0; i < 512; ++i) s += wrow[i] * tfl[i * 25 + u];
    qkP[idx] = s;
  } else {
    int cb = b - 100;                           // 0..63
    for (int i = cb * 256 + tid; i < 16384; i += 64 * 256) {
      WvP[i] = f2bf(Wv[i]);
    }
    for (int i = cb * 256 + tid; i < 131072; i += 64 * 256) {
      WoP[i] = f2bf(Wo[i]);
    }
  }
}

// ---------------------------------------------------------------------------
// Kernel 1b: energy + softmax per head -> attnP (zero-padded B-layout).
__global__ void k_attn(const float* __restrict__ qkP,
                       unsigned short* __restrict__ attnP)
{
  __shared__ float ql[1600], kl[1600], attl[625];
  const int h = blockIdx.x, tid = threadIdx.x;
  for (int i = tid; i < 1600; i += 256) {
    ql[i] = qkP[h * 1600 + i];
    kl[i] = qkP[12800 + h * 1600 + i];
  }
  __syncthreads();
  if (tid < 25) {
    int u = tid;
    float e[25];
    float mx = -1e30f;
    #pragma unroll
    for (int v = 0; v < 25; ++v) {
      float s = 0.f;
      #pragma unroll
      for (int r = 0; r < 64; ++r) s += ql[r * 25 + u] * kl[r * 25 + v];
      s *= 0.125f;
      e[v] = s;
      mx = fmaxf(mx, s);
    }
    float den = 0.f;
    #pragma unroll
    for (int v = 0; v < 25; ++v) { e[v] = __expf(e[v] - mx); den += e[v]; }
    float inv = 1.f / den;
    #pragma unroll
    for (int v = 0; v < 25; ++v) attl[u * 25 + v] = e[v] * inv;
  }
  __syncthreads();
  for (int i = tid; i < 1280; i += 256) {
    int vp = i / 40, u = i - 40 * vp;
    attnP[h * 1280 + i] =
        (vp < 25 && u < 25) ? f2bf(attl[u * 25 + vp]) : (unsigned short)0;
  }
}

// ---------------------------------------------------------------------------
// k_vm: V = Wv@F + bv for one (n, 2-t) tile -> Vws[n][t][c'][32] bf16.
// 256 threads (4 waves), LDS 33792 B -> 4 WGs/CU (4 waves/SIMD). 1 barrier.
__launch_bounds__(256)
__attribute__((amdgpu_waves_per_eu(4, 4)))
__global__ void k_vm(const float* __restrict__ feature,
                     const float* __restrict__ bv,
                     const unsigned short* __restrict__ WvP,
                     unsigned short* __restrict__ Vws)
{
  __shared__ unsigned short Fl[64 * 264];       // [col=(t*32+vp)][c]
  const int tid  = threadIdx.x;
  const int wave = tid >> 6;                    // = M-tile (c' tile)
  const int lane = tid & 63;
  const int quad = lane >> 4;
  const int l16  = lane & 15;
  const int n    = blockIdx.x & 7;
  const int tile = blockIdx.x >> 3;             // 0..511
  const int t0   = tile * 2;

  // zero pad cols (vp 25..31, both t)
  {
    short8 z = {0, 0, 0, 0, 0, 0, 0, 0};
    for (int i = tid; i < 448; i += 256) {      // 14 cols x 32 short8
      int pc = i >> 5, off = i & 31;
      int t = pc / 7, vp = 25 + (pc - 7 * t);
      *reinterpret_cast<short8*>(&Fl[(t * 32 + vp) * 264 + off * 8]) = z;
    }
  }

  // stage: thread owns channel c = tid; 50 floats (2 t x 25 v), as 25 float2
  {
    const int c = tid;
    const float2* s2 = reinterpret_cast<const float2*>(
        feature + ((size_t)(n * 256 + c) * 1024 + t0) * 25);
    float2 buf[13];
    #pragma unroll
    for (int j = 0; j < 13; ++j) buf[j] = s2[j];
    #pragma unroll
    for (int j = 0; j < 13; ++j) {
      int f0 = 2 * j;
      { int t = f0 / 25, vp = f0 - 25 * t;  Fl[(t * 32 + vp) * 264 + c] = f2bf(buf[j].x); }
      { int f1 = f0 + 1; int t = f1 / 25, vp = f1 - 25 * t;
        Fl[(t * 32 + vp) * 264 + c] = f2bf(buf[j].y); }
    }
    #pragma unroll
    for (int j = 0; j < 12; ++j) buf[j] = s2[13 + j];
    #pragma unroll
    for (int j = 0; j < 12; ++j) {
      int f0 = 26 + 2 * j;
      { int t = f0 / 25, vp = f0 - 25 * t;  Fl[(t * 32 + vp) * 264 + c] = f2bf(buf[j].x); }
      { int f1 = f0 + 1; int t = f1 / 25, vp = f1 - 25 * t;
        Fl[(t * 32 + vp) * 264 + c] = f2bf(buf[j].y); }
    }
  }
  __syncthreads();

  // GEMM: M=64 (wave = 16-row tile), N=64 cols, K=256. Wv streamed dist-2.
  const unsigned short* wvb = WvP + (wave * 16 + l16) * 256 + quad * 8;
  f4v acc[4];
  #pragma unroll
  for (int r = 0; r < 4; ++r) {
    float b = bv[wave * 16 + quad * 4 + r];
    #pragma unroll
    for (int ni = 0; ni < 4; ++ni) acc[ni][r] = b;
  }
  short8 wap[2];
  wap[0] = *reinterpret_cast<const short8*>(wvb);
  wap[1] = *reinterpret_cast<const short8*>(wvb + 32);
  #pragma unroll
  for (int ks = 0; ks < 8; ++ks) {
    short8 a = wap[ks & 1];
    if (ks < 6)
      wap[ks & 1] = *reinterpret_cast<const short8*>(wvb + (ks + 2) * 32);
    #pragma unroll
    for (int ni = 0; ni < 4; ++ni) {
      short8 b = *reinterpret_cast<const short8*>(
          &Fl[(ni * 16 + l16) * 264 + ks * 32 + quad * 8]);
      acc[ni] = __builtin_amdgcn_mfma_f32_16x16x32_bf16(a, b, acc[ni], 0, 0, 0);
    }
  }

  // write V (includes u-pads 25..31: finite values; zeroed by attnP pad in G2)
  #pragma unroll
  for (int ni = 0; ni < 4; ++ni) {
    int col = ni * 16 + l16;
    int t = col >> 5, u = col & 31;
    unsigned short* dst = Vws + ((size_t)(n * 1024 + t0 + t) * 64) * 32 + u;
    #pragma unroll
    for (int r = 0; r < 4; ++r)
      dst[(wave * 16 + quad * 4 + r) * 32] = f2bf(acc[ni][r]);
  }
}

// ---------------------------------------------------------------------------
// k_main: one 64-col tile: GEMM2 (V from global) -> Zl -> bar -> GEMM3.
// 512 threads (8 waves), LDS 66560 B -> 2 WGs/CU (4 waves/SIMD). 1 barrier.
__launch_bounds__(512)
__attribute__((amdgpu_waves_per_eu(4, 4)))
__global__ void k_main(const float* __restrict__ feature,
                       const float* __restrict__ bo,
                       const unsigned short* __restrict__ WoP,
                       const unsigned short* __restrict__ attnP,
                       const unsigned short* __restrict__ Vws,
                       float* __restrict__ out)
{
  extern __shared__ char smem[];
  unsigned short* Zl = (unsigned short*)smem;   // [64 col][520] (k 0..511)

  const int tid  = threadIdx.x;
  const int wave = tid >> 6;
  const int lane = tid & 63;
  const int quad = lane >> 4;
  const int l16  = lane & 15;
  const int n    = blockIdx.x & 7;
  const int tile = blockIdx.x >> 3;             // 0..511
  const int t0   = tile * 2;
  const int h    = wave;                        // one head per wave

  // GEMM2: Z[k=h*64+c'][col=(t,v)] = sum_u V[c',t,u] * attn_h[u,v]
  short8 ab[2];
  #pragma unroll
  for (int vt = 0; vt < 2; ++vt)
    ab[vt] = *reinterpret_cast<const short8*>(
        attnP + h * 1280 + (vt * 16 + l16) * 40 + quad * 8);

  const unsigned short* vbase =
      Vws + ((size_t)(n * 1024 + t0) * 64) * 32 + quad * 8;
  #pragma unroll
  for (int ct = 0; ct < 4; ++ct) {
    #pragma unroll
    for (int t = 0; t < 2; ++t) {
      short8 a = *reinterpret_cast<const short8*>(
          vbase + (size_t)t * 2048 + (ct * 16 + l16) * 32);
      #pragma unroll
      for (int vt = 0; vt < 2; ++vt) {
        f4v z0 = {0.f, 0.f, 0.f, 0.f};
        f4v az = __builtin_amdgcn_mfma_f32_16x16x32_bf16(a, ab[vt], z0, 0, 0, 0);
        int col = t * 32 + vt * 16 + l16;
        int k0 = h * 64 + ct * 16 + quad * 4;
        short4v zz;
        #pragma unroll
        for (int r = 0; r < 4; ++r) zz[r] = (short)f2bf(az[r]);
        *reinterpret_cast<short4v*>(&Zl[col * 520 + k0]) = zz;
      }
    }
  }

  // acc init: bias + residual (global reads overlap the barrier wait)
  f4v acc[2][4];
  #pragma unroll
  for (int mi = 0; mi < 2; ++mi) {
    const int o0 = wave * 32 + mi * 16 + quad * 4;
    #pragma unroll
    for (int r = 0; r < 4; ++r) {
      float bor = bo[o0 + r];
      const float* frow = feature + ((size_t)(n * 256 + o0 + r) * 1024 + t0) * 25;
      #pragma unroll
      for (int ni = 0; ni < 4; ++ni) {
        int colb = ni * 16 + l16;
        int t = colb >> 5, vp = colb & 31;
        float res = (vp < 25) ? frow[t * 25 + vp] : 0.f;
        acc[mi][ni][r] = bor + res;
      }
    }
  }
  __syncthreads();                              // the only barrier

  // GEMM3: acc += Wo @ Z, K=512, rolling distance-2 Wo prefetch from L2.
  const unsigned short* wob = WoP + (wave * 32 + l16) * 512 + quad * 8;
  short8 wop[2][2];                             // [parity][mi]
  wop[0][0] = *reinterpret_cast<const short8*>(wob);
  wop[0][1] = *reinterpret_cast<const short8*>(wob + 8192);
  wop[1][0] = *reinterpret_cast<const short8*>(wob + 32);
  wop[1][1] = *reinterpret_cast<const short8*>(wob + 8192 + 32);
  #pragma unroll
  for (int ks = 0; ks < 16; ++ks) {
    short8 w0 = wop[ks & 1][0];
    short8 w1 = wop[ks & 1][1];
    if (ks < 14) {
      wop[ks & 1][0] = *reinterpret_cast<const short8*>(wob + (ks + 2) * 32);
      wop[ks & 1][1] = *reinterpret_cast<const short8*>(wob + 8192 + (ks + 2) * 32);
    }
    #pragma unroll
    for (int ni = 0; ni < 4; ++ni) {
      short8 bfr = *reinterpret_cast<const short8*>(
          &Zl[(ni * 16 + l16) * 520 + ks * 32 + quad * 8]);
      acc[0][ni] = __builtin_amdgcn_mfma_f32_16x16x32_bf16(w0, bfr, acc[0][ni], 0, 0, 0);
      acc[1][ni] = __builtin_amdgcn_mfma_f32_16x16x32_bf16(w1, bfr, acc[1][ni], 0, 0, 0);
    }
  }

  // stores
  #pragma unroll
  for (int ni = 0; ni < 4; ++ni) {
    int colb = ni * 16 + l16;
    int t = colb >> 5, vp = colb & 31;
    if (vp < 25) {
      #pragma unroll
      for (int mi = 0; mi < 2; ++mi)
        #pragma unroll
        for (int r = 0; r < 4; ++r) {
          int o = wave * 32 + mi * 16 + quad * 4 + r;
          out[((size_t)(n * 256 + o) * 1024 + (t0 + t)) * 25 + vp] = acc[mi][ni][r];
        }
    }
  }
}

// ---------------------------------------------------------------------------
extern "C" void kernel_launch(void* const* d_in, const int* in_sizes, int n_in,
                              void* d_out, int out_size, void* d_ws, size_t ws_size,
                              hipStream_t stream)
{
  const float* feature = (const float*)d_in[0];
  const float* tf      = (const float*)d_in[1];
  const float* Wq      = (const float*)d_in[2];
  const float* bq      = (const float*)d_in[3];
  const float* Wk      = (const float*)d_in[4];
  const float* bk      = (const float*)d_in[5];
  const float* Wv      = (const float*)d_in[6];
  const float* bv      = (const float*)d_in[7];
  const float* Wo      = (const float*)d_in[8];
  const float* bo      = (const float*)d_in[9];
  float* out = (float*)d_out;

  unsigned short* WvP   = (unsigned short*)d_ws;        // 16384
  unsigned short* WoP   = WvP + 16384;                  // 131072
  unsigned short* attnP = WoP + 131072;                 // 10240
  float* qkP = (float*)(attnP + 10240);                 // 25600 floats
  unsigned short* Vws   = (unsigned short*)(qkP + 25600);  // 16777216 elems

  hipLaunchKernelGGL(k_qk_conv, dim3(164), dim3(256), 0, stream,
                     tf, Wq, bq, Wk, bk, Wv, Wo, WvP, WoP, qkP);
  hipLaunchKernelGGL(k_attn, dim3(8), dim3(256), 0, stream, qkP, attnP);

  hipLaunchKernelGGL(k_vm, dim3(4096), dim3(256), 0, stream,
                     feature, bv, WvP, Vws);

  hipFuncSetAttribute(reinterpret_cast<const void*>(&k_main),
                      hipFuncAttributeMaxDynamicSharedMemorySize, 66560);
  hipLaunchKernelGGL(k_main, dim3(4096), dim3(512), 66560, stream,
                     feature, bo, WoP, attnP, Vws, out);
}